// Round 6
// baseline (1864.986 us; speedup 1.0000x reference)
//
#include <hip/hip_runtime.h>
#include <stdint.h>

typedef unsigned short u16;
typedef unsigned int   u32;

#define WW 512
#define HH 512
#define BB 4
#define CC 32
#define EPSW 1e-3f

typedef __bf16 bf16x8 __attribute__((ext_vector_type(8)));
typedef short  s16x8  __attribute__((ext_vector_type(8)));
typedef float  f32x4  __attribute__((ext_vector_type(4)));

union BU { u16 h[8]; u32 u[4]; bf16x8 b; s16x8 s; };

__device__ __forceinline__ int reflect512(int i) {
    i = (i < 0) ? -i : i;
    return (i >= WW) ? (2*WW - 2 - i) : i;
}
__device__ __forceinline__ u16 f2bf(float f) {
    u32 u = __float_as_uint(f);
    return (u16)((u + 0x7fffu + ((u >> 16) & 1u)) >> 16);
}

// ---------------- horizontal pass (unchanged from R5, passed) ---------------
__global__ __launch_bounds__(256, 4)
void hpass(const float* __restrict__ x, const float* __restrict__ sig,
           u32* __restrict__ ws)
{
    __shared__ float xs[32*132];
    const int t  = threadIdx.x;
    const int wt = blockIdx.x;
    const int h  = blockIdx.y;
    const int b  = blockIdx.z;
    const int wbase = wt*64 - 32;

    {
        const int wi = t & 127;
        const int gw = reflect512(wbase + wi);
        #pragma unroll
        for (int rep = 0; rep < 16; ++rep) {
            int c = rep*2 + (t >> 7);
            xs[c*132 + wi] = x[((size_t)((b*CC + c)*HH + h))*WW + gw];
        }
    }
    __syncthreads();

    const int c0  = (t & 7)*4;
    const int wp  = t >> 3;
    const int w0g = wt*64 + wp*2;
    const int bi0 = 32 + wp*2;

    float2 sg = *(const float2*)(sig + ((size_t)(b*HH + h))*WW + w0g);

    float m1[2], q1[2], wv1[2], S1[2], m2[2], q2[2], wv2[2], S2[2];
    #pragma unroll
    for (int p = 0; p < 2; ++p) {
        float s   = p ? sg.y : sg.x;
        float tt1 = -0.5f / (s*s);
        m1[p] = __expf(tt1);             q1[p] = m1[p]*m1[p];
        float tt2 = tt1 * 0.390625f;
        m2[p] = __expf(tt2);             q2[p] = m2[p]*m2[p];
        wv1[p] = 1.f; wv2[p] = 1.f; S1[p] = 0.f; S2[p] = 0.f;
    }

    float a1[4][2], a2[4][2];
    float2 Lhi[4], Rlo[4];
    #pragma unroll
    for (int c = 0; c < 4; ++c) {
        float2 Cq = *(const float2*)&xs[(c0+c)*132 + bi0];
        a1[c][0] = Cq.x; a1[c][1] = Cq.y;
        a2[c][0] = Cq.x; a2[c][1] = Cq.y;
        Lhi[c] = Cq; Rlo[c] = Cq;
    }

    #pragma unroll 1
    for (int kb = 0; kb < 15; ++kb) {
        float tw1[2][2], tw2[2][2];
        #pragma unroll
        for (int j = 0; j < 2; ++j)
            #pragma unroll
            for (int p = 0; p < 2; ++p) {
                wv1[p] *= m1[p]; m1[p] *= q1[p];
                float ta = (wv1[p] >= EPSW) ? wv1[p] : 0.f;
                tw1[j][p] = ta; S1[p] += ta;
                wv2[p] *= m2[p]; m2[p] *= q2[p];
                float tb = (wv2[p] >= EPSW) ? wv2[p] : 0.f;
                tw2[j][p] = tb; S2[p] += tb;
            }
        const int li = bi0 - 2 - 2*kb;
        const int ri = bi0 + 2 + 2*kb;
        #pragma unroll
        for (int c = 0; c < 4; ++c) {
            float2 Llo = *(const float2*)&xs[(c0+c)*132 + li];
            float2 Rhi = *(const float2*)&xs[(c0+c)*132 + ri];
            float s00 = Llo.y    + Rlo[c].y;
            float s01 = Llo.x    + Rhi.x;
            float s10 = Lhi[c].x + Rhi.x;
            float s11 = Llo.y    + Rhi.y;
            a1[c][0] = fmaf(tw1[0][0], s00, a1[c][0]);
            a1[c][0] = fmaf(tw1[1][0], s01, a1[c][0]);
            a1[c][1] = fmaf(tw1[0][1], s10, a1[c][1]);
            a1[c][1] = fmaf(tw1[1][1], s11, a1[c][1]);
            a2[c][0] = fmaf(tw2[0][0], s00, a2[c][0]);
            a2[c][0] = fmaf(tw2[1][0], s01, a2[c][0]);
            a2[c][1] = fmaf(tw2[0][1], s10, a2[c][1]);
            a2[c][1] = fmaf(tw2[1][1], s11, a2[c][1]);
            Lhi[c] = Llo; Rlo[c] = Rhi;
        }
    }

    {
        float t1e[2], t2e[2];
        #pragma unroll
        for (int p = 0; p < 2; ++p) {
            wv1[p] *= m1[p];
            float ta = (wv1[p] >= EPSW) ? wv1[p] : 0.f;
            t1e[p] = ta; S1[p] += ta;
            wv2[p] *= m2[p];
            float tb = (wv2[p] >= EPSW) ? wv2[p] : 0.f;
            t2e[p] = tb; S2[p] += tb;
        }
        const int li = bi0 - 32;
        const int ri = bi0 + 32;
        #pragma unroll
        for (int c = 0; c < 4; ++c) {
            float2 Lle = *(const float2*)&xs[(c0+c)*132 + li];
            float2 Rre = *(const float2*)&xs[(c0+c)*132 + ri];
            float s0 = Lle.y    + Rlo[c].y;
            float s1 = Lhi[c].x + Rre.x;
            a1[c][0] = fmaf(t1e[0], s0, a1[c][0]);
            a1[c][1] = fmaf(t1e[1], s1, a1[c][1]);
            a2[c][0] = fmaf(t2e[0], s0, a2[c][0]);
            a2[c][1] = fmaf(t2e[1], s1, a2[c][1]);
        }
    }

    float n1[2], n2[2];
    #pragma unroll
    for (int p = 0; p < 2; ++p) {
        n1[p] = 1.0f / (1.0f + 2.0f*S1[p] + 1e-8f);
        n2[p] = 1.0f / (1.0f + 2.0f*S2[p] + 1e-8f);
    }
    #pragma unroll
    for (int p = 0; p < 2; ++p) {
        uint4 pk;
        u32* pq = (u32*)&pk;
        #pragma unroll
        for (int c = 0; c < 4; ++c)
            pq[c] = (u32)f2bf(a1[c][p]*n1[p]) | ((u32)f2bf(a2[c][p]*n2[p]) << 16);
        *(uint4*)(ws + ((size_t)(b*HH + h)*WW + (w0g + p))*CC + c0) = pk;
    }
}

// ---------------- vertical pass (MFMA, K-streamed): ws -> out ---------------
// grid (32 = wg*2+chalf, 8 hblk, 4 b), block 1024 = 16 waves. Tile per block:
// 32 w x 64 h x 16 c (c-half), both gaussians. K window (128 rows) streamed
// in 4 chunks of 32 through one LDS buffer As[w32][c16][r32] pitch-33 u32
// (interleaved {g1,g2}); next chunk's global loads issued before compute.
// Wave wid owns w-pair {2wid, 2wid+1}. Full 128B-line output stores.
__global__ __launch_bounds__(1024)
void vpass(const u32* __restrict__ ws, const float* __restrict__ sig,
           float* __restrict__ out)
{
    extern __shared__ u32 As[];          // 16896 u32 = 67.6KB, aliased as f32 Dl
    const int t    = threadIdx.x;
    const int lane = t & 63;
    const int wid  = t >> 6;             // 0..15
    const int l15  = lane & 15;
    const int grp  = lane >> 4;

    const int bx    = blockIdx.x;
    const int chalf = bx & 1;
    const int w0    = (bx >> 1) * 32;
    const int h0    = blockIdx.y * 64;
    const int b     = blockIdx.z;
    const int c0    = chalf * 16;

    // sigma -> ttl[wsel][ht]
    float ttl[2][4];
    #pragma unroll
    for (int wsel = 0; wsel < 2; ++wsel)
        #pragma unroll
        for (int ht = 0; ht < 4; ++ht) {
            float s = sig[((size_t)(b*HH + h0 + ht*16 + l15))*WW + w0 + 2*wid + wsel];
            ttl[wsel][ht] = -0.5f / (s*s);
        }

    // staging decode: thread -> 4 uint4 chunks {t, t+1024, t+2048, t+3072}
    const int srow = t >> 7;             // 0..7 (row within 8-row group)
    const int rem  = t & 127;
    const int sw   = rem >> 2;           // 0..31 (w)
    const int sc4  = rem & 3;            // 0..3  (c quad)
    const u32* wsb = ws + (size_t)b * HH * WW * CC;

    uint4 v[4];
    #pragma unroll
    for (int i = 0; i < 4; ++i) {
        int hh = reflect512(h0 - 32 + srow + 8*i);
        v[i] = *(const uint4*)&wsb[(size_t)(hh*WW + w0 + sw)*CC + c0 + sc4*4];
    }

    f32x4 acc[2][2][4];                  // [wsel][g][ht]
    float Sr[2][2][4];
    #pragma unroll
    for (int a = 0; a < 2; ++a)
        #pragma unroll
        for (int g = 0; g < 2; ++g)
            #pragma unroll
            for (int ht = 0; ht < 4; ++ht) {
                acc[a][g][ht] = (f32x4){0.f,0.f,0.f,0.f};
                Sr[a][g][ht] = 0.f;
            }

    const int HT0[4] = {0, 0, 0, 2};
    const int HT1[4] = {1, 3, 3, 3};

    #pragma unroll
    for (int kt = 0; kt < 4; ++kt) {
        if (kt) __syncthreads();         // prev compute done, As free
        // LDS write, r-granule swizzled by (w&3): As[(w*16+c)*33 + swz(r)]
        #pragma unroll
        for (int i = 0; i < 4; ++i) {
            int rs = srow + 8*(i ^ (sw & 3));
            #pragma unroll
            for (int cc = 0; cc < 4; ++cc)
                As[(sw*16 + sc4*4 + cc)*33 + rs] = ((const u32*)&v[i])[cc];
        }
        if (kt < 3) {                    // issue next chunk (overlaps compute)
            #pragma unroll
            for (int i = 0; i < 4; ++i) {
                int hh = reflect512(h0 - 32 + (kt+1)*32 + srow + 8*i);
                v[i] = *(const uint4*)&wsb[(size_t)(hh*WW + w0 + sw)*CC + c0 + sc4*4];
            }
        }
        __syncthreads();

        #pragma unroll
        for (int wsel = 0; wsel < 2; ++wsel) {
            const int wl = 2*wid + wsel;
            // raw interleaved A: 8 u32 (r = grp*8 .. +7, granule-swizzled)
            u32 raw[8];
            {
                const int base = (wl*16 + l15)*33 + (grp ^ (wl & 3))*8;
                #pragma unroll
                for (int j = 0; j < 8; ++j) raw[j] = As[base + j];
            }
            #pragma unroll
            for (int g = 0; g < 2; ++g) {
                BU af;
                #pragma unroll
                for (int i = 0; i < 4; ++i)
                    af.u[i] = g ? ((raw[2*i] >> 16) | (raw[2*i+1] & 0xffff0000u))
                                : ((raw[2*i] & 0xffffu) | (raw[2*i+1] << 16));
                #pragma unroll
                for (int ht = 0; ht < 4; ++ht) {
                    if (ht < HT0[kt] || ht > HT1[kt]) continue;
                    const float tt = ttl[wsel][ht] * (g ? 0.390625f : 1.0f);
                    const int d0 = kt*32 + grp*8 - (ht*16 + l15) - 32;
                    BU bfr;
                    float Sl = 0.f;
                    #pragma unroll
                    for (int j = 0; j < 8; ++j) {
                        int d = d0 + j;
                        float wf = __expf(tt * (float)(d*d));
                        bool ok = ((u32)(d + 31) <= 62u) && (wf >= EPSW);
                        float val = ok ? wf : 0.f;
                        Sl += val;
                        bfr.h[j] = f2bf(val);
                    }
                    Sr[wsel][g][ht] += Sl;
                    acc[wsel][g][ht] = __builtin_amdgcn_mfma_f32_16x16x32_bf16(
                        af.b, bfr.b, acc[wsel][g][ht], 0, 0, 0);
                }
            }
        }
    }

    // normalize + diff into regs
    float dif[2][4][4];
    #pragma unroll
    for (int wsel = 0; wsel < 2; ++wsel)
        #pragma unroll
        for (int ht = 0; ht < 4; ++ht) {
            float n[2];
            #pragma unroll
            for (int g = 0; g < 2; ++g) {
                float S = Sr[wsel][g][ht];
                S += __shfl_xor(S, 16);
                S += __shfl_xor(S, 32);
                n[g] = 1.0f / (S + 1e-8f);
            }
            #pragma unroll
            for (int r = 0; r < 4; ++r)
                dif[wsel][ht][r] = acc[wsel][1][ht][r]*n[1] - acc[wsel][0][ht][r]*n[0];
        }

    // epilogue: two 32-h halves through LDS, full-line stores
    float* Dl = (float*)As;              // [c'16][h32] rows, w pitch 33
    #pragma unroll
    for (int hh = 0; hh < 2; ++hh) {
        __syncthreads();
        #pragma unroll
        for (int wsel = 0; wsel < 2; ++wsel)
            #pragma unroll
            for (int htl = 0; htl < 2; ++htl) {
                const int ht = hh*2 + htl;
                #pragma unroll
                for (int r = 0; r < 4; ++r)
                    Dl[((grp*4 + r)*32 + htl*16 + l15)*33 + 2*wid + wsel] = dif[wsel][ht][r];
            }
        __syncthreads();
        const int row  = t >> 1;         // 0..511 = c'(16) x h(32)
        const int cl   = row >> 5;
        const int hl   = row & 31;
        const int woff = (t & 1)*16;
        const float* src = &Dl[(cl*32 + hl)*33 + woff];
        float* dst = out + ((size_t)((b*CC + c0 + cl)*HH + h0 + hh*32 + hl))*WW + w0 + woff;
        #pragma unroll
        for (int k = 0; k < 4; ++k)
            *(float4*)(dst + 4*k) = *(const float4*)(src + 4*k);
    }
}

extern "C" void kernel_launch(void* const* d_in, const int* in_sizes, int n_in,
                              void* d_out, int out_size, void* d_ws, size_t ws_size,
                              hipStream_t stream) {
    const float* x   = (const float*)d_in[0];
    const float* sig = (const float*)d_in[1];
    float* out = (float*)d_out;

    const size_t n = (size_t)BB*CC*HH*WW;
    if (ws_size < n * sizeof(u32)) return;
    u32* ws = (u32*)d_ws;

    hpass<<<dim3(8, 512, 4), 256, 0, stream>>>(x, sig, ws);
    vpass<<<dim3(32, 8, 4), 1024, 16896*sizeof(u32), stream>>>(ws, sig, out);
}

// Round 7
// 952.764 us; speedup vs baseline: 1.9574x; 1.9574x over previous
//
#include <hip/hip_runtime.h>
#include <stdint.h>

typedef unsigned short u16;
typedef unsigned int   u32;

#define WW 512
#define HH 512
#define BB 4
#define CC 32
#define EPSW 1e-3f

typedef __bf16 bf16x8 __attribute__((ext_vector_type(8)));
typedef short  s16x8  __attribute__((ext_vector_type(8)));
typedef float  f32x4  __attribute__((ext_vector_type(4)));

union BU { u16 h[8]; u32 u[4]; bf16x8 b; s16x8 s; };

__device__ __forceinline__ int reflect512(int i) {
    i = (i < 0) ? -i : i;
    return (i >= WW) ? (2*WW - 2 - i) : i;
}
__device__ __forceinline__ u16 f2bf(float f) {
    u32 u = __float_as_uint(f);
    return (u16)((u + 0x7fffu + ((u >> 16) & 1u)) >> 16);
}

// ---------------- horizontal pass (unchanged, proven R5/R6) -----------------
__global__ __launch_bounds__(256, 4)
void hpass(const float* __restrict__ x, const float* __restrict__ sig,
           u32* __restrict__ ws)
{
    __shared__ float xs[32*132];
    const int t  = threadIdx.x;
    const int wt = blockIdx.x;
    const int h  = blockIdx.y;
    const int b  = blockIdx.z;
    const int wbase = wt*64 - 32;

    {
        const int wi = t & 127;
        const int gw = reflect512(wbase + wi);
        #pragma unroll
        for (int rep = 0; rep < 16; ++rep) {
            int c = rep*2 + (t >> 7);
            xs[c*132 + wi] = x[((size_t)((b*CC + c)*HH + h))*WW + gw];
        }
    }
    __syncthreads();

    const int c0  = (t & 7)*4;
    const int wp  = t >> 3;
    const int w0g = wt*64 + wp*2;
    const int bi0 = 32 + wp*2;

    float2 sg = *(const float2*)(sig + ((size_t)(b*HH + h))*WW + w0g);

    float m1[2], q1[2], wv1[2], S1[2], m2[2], q2[2], wv2[2], S2[2];
    #pragma unroll
    for (int p = 0; p < 2; ++p) {
        float s   = p ? sg.y : sg.x;
        float tt1 = -0.5f / (s*s);
        m1[p] = __expf(tt1);             q1[p] = m1[p]*m1[p];
        float tt2 = tt1 * 0.390625f;
        m2[p] = __expf(tt2);             q2[p] = m2[p]*m2[p];
        wv1[p] = 1.f; wv2[p] = 1.f; S1[p] = 0.f; S2[p] = 0.f;
    }

    float a1[4][2], a2[4][2];
    float2 Lhi[4], Rlo[4];
    #pragma unroll
    for (int c = 0; c < 4; ++c) {
        float2 Cq = *(const float2*)&xs[(c0+c)*132 + bi0];
        a1[c][0] = Cq.x; a1[c][1] = Cq.y;
        a2[c][0] = Cq.x; a2[c][1] = Cq.y;
        Lhi[c] = Cq; Rlo[c] = Cq;
    }

    #pragma unroll 1
    for (int kb = 0; kb < 15; ++kb) {
        float tw1[2][2], tw2[2][2];
        #pragma unroll
        for (int j = 0; j < 2; ++j)
            #pragma unroll
            for (int p = 0; p < 2; ++p) {
                wv1[p] *= m1[p]; m1[p] *= q1[p];
                float ta = (wv1[p] >= EPSW) ? wv1[p] : 0.f;
                tw1[j][p] = ta; S1[p] += ta;
                wv2[p] *= m2[p]; m2[p] *= q2[p];
                float tb = (wv2[p] >= EPSW) ? wv2[p] : 0.f;
                tw2[j][p] = tb; S2[p] += tb;
            }
        const int li = bi0 - 2 - 2*kb;
        const int ri = bi0 + 2 + 2*kb;
        #pragma unroll
        for (int c = 0; c < 4; ++c) {
            float2 Llo = *(const float2*)&xs[(c0+c)*132 + li];
            float2 Rhi = *(const float2*)&xs[(c0+c)*132 + ri];
            float s00 = Llo.y    + Rlo[c].y;
            float s01 = Llo.x    + Rhi.x;
            float s10 = Lhi[c].x + Rhi.x;
            float s11 = Llo.y    + Rhi.y;
            a1[c][0] = fmaf(tw1[0][0], s00, a1[c][0]);
            a1[c][0] = fmaf(tw1[1][0], s01, a1[c][0]);
            a1[c][1] = fmaf(tw1[0][1], s10, a1[c][1]);
            a1[c][1] = fmaf(tw1[1][1], s11, a1[c][1]);
            a2[c][0] = fmaf(tw2[0][0], s00, a2[c][0]);
            a2[c][0] = fmaf(tw2[1][0], s01, a2[c][0]);
            a2[c][1] = fmaf(tw2[0][1], s10, a2[c][1]);
            a2[c][1] = fmaf(tw2[1][1], s11, a2[c][1]);
            Lhi[c] = Llo; Rlo[c] = Rhi;
        }
    }

    {
        float t1e[2], t2e[2];
        #pragma unroll
        for (int p = 0; p < 2; ++p) {
            wv1[p] *= m1[p];
            float ta = (wv1[p] >= EPSW) ? wv1[p] : 0.f;
            t1e[p] = ta; S1[p] += ta;
            wv2[p] *= m2[p];
            float tb = (wv2[p] >= EPSW) ? wv2[p] : 0.f;
            t2e[p] = tb; S2[p] += tb;
        }
        const int li = bi0 - 32;
        const int ri = bi0 + 32;
        #pragma unroll
        for (int c = 0; c < 4; ++c) {
            float2 Lle = *(const float2*)&xs[(c0+c)*132 + li];
            float2 Rre = *(const float2*)&xs[(c0+c)*132 + ri];
            float s0 = Lle.y    + Rlo[c].y;
            float s1 = Lhi[c].x + Rre.x;
            a1[c][0] = fmaf(t1e[0], s0, a1[c][0]);
            a1[c][1] = fmaf(t1e[1], s1, a1[c][1]);
            a2[c][0] = fmaf(t2e[0], s0, a2[c][0]);
            a2[c][1] = fmaf(t2e[1], s1, a2[c][1]);
        }
    }

    float n1[2], n2[2];
    #pragma unroll
    for (int p = 0; p < 2; ++p) {
        n1[p] = 1.0f / (1.0f + 2.0f*S1[p] + 1e-8f);
        n2[p] = 1.0f / (1.0f + 2.0f*S2[p] + 1e-8f);
    }
    #pragma unroll
    for (int p = 0; p < 2; ++p) {
        uint4 pk;
        u32* pq = (u32*)&pk;
        #pragma unroll
        for (int c = 0; c < 4; ++c)
            pq[c] = (u32)f2bf(a1[c][p]*n1[p]) | ((u32)f2bf(a2[c][p]*n2[p]) << 16);
        *(uint4*)(ws + ((size_t)(b*HH + h)*WW + (w0g + p))*CC + c0) = pk;
    }
}

// ---------------- vertical pass (MFMA, K-streamed, register-sized) ----------
// grid (32 = wg*2+chalf, 16 hblk, 4 b), block 1024 = 16 waves. Tile: 32w x
// 32h x 16c (c-half), both gaussians. K window 96 rows streamed in 3 chunks
// of 32 through LDS As[(w*16+c)*33 + r] (interleaved u32), prefetch in regs.
// Wave wid owns w-pair {2wid, 2wid+1}. acc[2][2][2] f32x4 = 32 VGPR; total
// live ~105 -> fits 128-VGPR cap from __launch_bounds__(1024, 4). No spills.
__global__ __launch_bounds__(1024, 4)
void vpass(const u32* __restrict__ ws, const float* __restrict__ sig,
           float* __restrict__ out)
{
    extern __shared__ u32 As[];          // 16896 u32 = 67.6KB, aliased as f32 Dl
    const int t    = threadIdx.x;
    const int lane = t & 63;
    const int wid  = t >> 6;             // 0..15
    const int l15  = lane & 15;
    const int grp  = lane >> 4;

    const int bx    = blockIdx.x;
    const int chalf = bx & 1;
    const int w0    = (bx >> 1) * 32;
    const int h0    = blockIdx.y * 32;
    const int b     = blockIdx.z;
    const int c0    = chalf * 16;

    float ttl[2][2];
    #pragma unroll
    for (int wsel = 0; wsel < 2; ++wsel)
        #pragma unroll
        for (int ht = 0; ht < 2; ++ht) {
            float s = sig[((size_t)(b*HH + h0 + ht*16 + l15))*WW + w0 + 2*wid + wsel];
            ttl[wsel][ht] = -0.5f / (s*s);
        }

    const int srow = t >> 7;             // 0..7
    const int rem  = t & 127;
    const int sw   = rem >> 2;           // 0..31 (w)
    const int sc4  = rem & 3;            // 0..3  (c quad)
    const u32* wsb = ws + (size_t)b * HH * WW * CC;

    uint4 v[4];
    #pragma unroll
    for (int i = 0; i < 4; ++i) {
        int hh = reflect512(h0 - 32 + srow + 8*i);
        v[i] = *(const uint4*)&wsb[(size_t)(hh*WW + w0 + sw)*CC + c0 + sc4*4];
    }

    f32x4 acc[2][2][2];                  // [wsel][g][ht]
    float Sr[2][2][2];
    #pragma unroll
    for (int a = 0; a < 2; ++a)
        #pragma unroll
        for (int g = 0; g < 2; ++g)
            #pragma unroll
            for (int ht = 0; ht < 2; ++ht) {
                acc[a][g][ht] = (f32x4){0.f,0.f,0.f,0.f};
                Sr[a][g][ht] = 0.f;
            }

    #pragma unroll
    for (int kt = 0; kt < 3; ++kt) {
        if (kt) __syncthreads();
        #pragma unroll
        for (int i = 0; i < 4; ++i) {
            int rs = srow + 8*(i ^ (sw & 3));
            #pragma unroll
            for (int cc = 0; cc < 4; ++cc)
                As[(sw*16 + sc4*4 + cc)*33 + rs] = ((const u32*)&v[i])[cc];
        }
        if (kt < 2) {
            #pragma unroll
            for (int i = 0; i < 4; ++i) {
                int hh = reflect512(h0 - 32 + (kt+1)*32 + srow + 8*i);
                v[i] = *(const uint4*)&wsb[(size_t)(hh*WW + w0 + sw)*CC + c0 + sc4*4];
            }
        }
        __syncthreads();

        #pragma unroll
        for (int wsel = 0; wsel < 2; ++wsel) {
            const int wl = 2*wid + wsel;
            u32 raw[8];
            {
                const int base = (wl*16 + l15)*33 + (grp ^ (wl & 3))*8;
                #pragma unroll
                for (int j = 0; j < 8; ++j) raw[j] = As[base + j];
            }
            #pragma unroll
            for (int g = 0; g < 2; ++g) {
                BU af;
                #pragma unroll
                for (int i = 0; i < 4; ++i)
                    af.u[i] = g ? ((raw[2*i] >> 16) | (raw[2*i+1] & 0xffff0000u))
                                : ((raw[2*i] & 0xffffu) | (raw[2*i+1] << 16));
                #pragma unroll
                for (int ht = 0; ht < 2; ++ht) {
                    const float tt = ttl[wsel][ht] * (g ? 0.390625f : 1.0f);
                    const int d0 = kt*32 + grp*8 - (ht*16 + l15) - 32;
                    BU bfr;
                    float Sl = 0.f;
                    #pragma unroll
                    for (int j = 0; j < 8; ++j) {
                        int d = d0 + j;
                        float wf = __expf(tt * (float)(d*d));
                        bool ok = ((u32)(d + 31) <= 62u) && (wf >= EPSW);
                        float val = ok ? wf : 0.f;
                        Sl += val;
                        bfr.h[j] = f2bf(val);
                    }
                    Sr[wsel][g][ht] += Sl;
                    acc[wsel][g][ht] = __builtin_amdgcn_mfma_f32_16x16x32_bf16(
                        af.b, bfr.b, acc[wsel][g][ht], 0, 0, 0);
                }
            }
        }
    }

    // normalize + diff
    float dif[2][2][4];
    #pragma unroll
    for (int wsel = 0; wsel < 2; ++wsel)
        #pragma unroll
        for (int ht = 0; ht < 2; ++ht) {
            float n[2];
            #pragma unroll
            for (int g = 0; g < 2; ++g) {
                float S = Sr[wsel][g][ht];
                S += __shfl_xor(S, 16);
                S += __shfl_xor(S, 32);
                n[g] = 1.0f / (S + 1e-8f);
            }
            #pragma unroll
            for (int r = 0; r < 4; ++r)
                dif[wsel][ht][r] = acc[wsel][1][ht][r]*n[1] - acc[wsel][0][ht][r]*n[0];
        }

    // epilogue: transpose through LDS, full-128B-line stores
    __syncthreads();
    float* Dl = (float*)As;              // [c'16 x h32] rows, w pitch 33
    #pragma unroll
    for (int wsel = 0; wsel < 2; ++wsel)
        #pragma unroll
        for (int ht = 0; ht < 2; ++ht)
            #pragma unroll
            for (int r = 0; r < 4; ++r)
                Dl[((grp*4 + r)*32 + ht*16 + l15)*33 + 2*wid + wsel] = dif[wsel][ht][r];
    __syncthreads();
    {
        const int row  = t >> 1;         // 0..511 = c'(16) x h(32)
        const int cl   = row >> 5;
        const int hl   = row & 31;
        const int woff = (t & 1)*16;
        const float* src = &Dl[(cl*32 + hl)*33 + woff];
        float* dst = out + ((size_t)((b*CC + c0 + cl)*HH + h0 + hl))*WW + w0 + woff;
        #pragma unroll
        for (int k = 0; k < 4; ++k)
            *(float4*)(dst + 4*k) = *(const float4*)(src + 4*k);
    }
}

extern "C" void kernel_launch(void* const* d_in, const int* in_sizes, int n_in,
                              void* d_out, int out_size, void* d_ws, size_t ws_size,
                              hipStream_t stream) {
    const float* x   = (const float*)d_in[0];
    const float* sig = (const float*)d_in[1];
    float* out = (float*)d_out;

    const size_t n = (size_t)BB*CC*HH*WW;
    if (ws_size < n * sizeof(u32)) return;
    u32* ws = (u32*)d_ws;

    hpass<<<dim3(8, 512, 4), 256, 0, stream>>>(x, sig, ws);
    vpass<<<dim3(32, 16, 4), 1024, 16896*sizeof(u32), stream>>>(ws, sig, out);
}

// Round 8
// 946.032 us; speedup vs baseline: 1.9714x; 1.0071x over previous
//
#include <hip/hip_runtime.h>
#include <stdint.h>

typedef unsigned short u16;
typedef unsigned int   u32;

#define WW 512
#define HH 512
#define BB 4
#define CC 32
#define EPSW 1e-3f

typedef __bf16 bf16x8 __attribute__((ext_vector_type(8)));
typedef short  s16x8  __attribute__((ext_vector_type(8)));
typedef float  f32x4  __attribute__((ext_vector_type(4)));

union BU { u16 h[8]; u32 u[4]; bf16x8 b; s16x8 s; };

__device__ __forceinline__ int reflect512(int i) {
    i = (i < 0) ? -i : i;
    return (i >= WW) ? (2*WW - 2 - i) : i;
}
__device__ __forceinline__ u16 f2bf(float f) {
    u32 u = __float_as_uint(f);
    return (u16)((u + 0x7fffu + ((u >> 16) & 1u)) >> 16);
}

// ---------------- horizontal pass (logic proven R5-R7; no VGPR cap) ---------
__global__ __launch_bounds__(256)
void hpass(const float* __restrict__ x, const float* __restrict__ sig,
           u32* __restrict__ ws)
{
    __shared__ float xs[32*132];
    const int t  = threadIdx.x;
    const int wt = blockIdx.x;
    const int h  = blockIdx.y;
    const int b  = blockIdx.z;
    const int wbase = wt*64 - 32;

    {
        const int wi = t & 127;
        const int gw = reflect512(wbase + wi);
        #pragma unroll
        for (int rep = 0; rep < 16; ++rep) {
            int c = rep*2 + (t >> 7);
            xs[c*132 + wi] = x[((size_t)((b*CC + c)*HH + h))*WW + gw];
        }
    }
    __syncthreads();

    const int c0  = (t & 7)*4;
    const int wp  = t >> 3;
    const int w0g = wt*64 + wp*2;
    const int bi0 = 32 + wp*2;

    float2 sg = *(const float2*)(sig + ((size_t)(b*HH + h))*WW + w0g);

    float m1[2], q1[2], wv1[2], S1[2], m2[2], q2[2], wv2[2], S2[2];
    #pragma unroll
    for (int p = 0; p < 2; ++p) {
        float s   = p ? sg.y : sg.x;
        float tt1 = -0.5f / (s*s);
        m1[p] = __expf(tt1);             q1[p] = m1[p]*m1[p];
        float tt2 = tt1 * 0.390625f;
        m2[p] = __expf(tt2);             q2[p] = m2[p]*m2[p];
        wv1[p] = 1.f; wv2[p] = 1.f; S1[p] = 0.f; S2[p] = 0.f;
    }

    float a1[4][2], a2[4][2];
    float2 Lhi[4], Rlo[4];
    #pragma unroll
    for (int c = 0; c < 4; ++c) {
        float2 Cq = *(const float2*)&xs[(c0+c)*132 + bi0];
        a1[c][0] = Cq.x; a1[c][1] = Cq.y;
        a2[c][0] = Cq.x; a2[c][1] = Cq.y;
        Lhi[c] = Cq; Rlo[c] = Cq;
    }

    #pragma unroll 1
    for (int kb = 0; kb < 15; ++kb) {
        float tw1[2][2], tw2[2][2];
        #pragma unroll
        for (int j = 0; j < 2; ++j)
            #pragma unroll
            for (int p = 0; p < 2; ++p) {
                wv1[p] *= m1[p]; m1[p] *= q1[p];
                float ta = (wv1[p] >= EPSW) ? wv1[p] : 0.f;
                tw1[j][p] = ta; S1[p] += ta;
                wv2[p] *= m2[p]; m2[p] *= q2[p];
                float tb = (wv2[p] >= EPSW) ? wv2[p] : 0.f;
                tw2[j][p] = tb; S2[p] += tb;
            }
        const int li = bi0 - 2 - 2*kb;
        const int ri = bi0 + 2 + 2*kb;
        #pragma unroll
        for (int c = 0; c < 4; ++c) {
            float2 Llo = *(const float2*)&xs[(c0+c)*132 + li];
            float2 Rhi = *(const float2*)&xs[(c0+c)*132 + ri];
            float s00 = Llo.y    + Rlo[c].y;
            float s01 = Llo.x    + Rhi.x;
            float s10 = Lhi[c].x + Rhi.x;
            float s11 = Llo.y    + Rhi.y;
            a1[c][0] = fmaf(tw1[0][0], s00, a1[c][0]);
            a1[c][0] = fmaf(tw1[1][0], s01, a1[c][0]);
            a1[c][1] = fmaf(tw1[0][1], s10, a1[c][1]);
            a1[c][1] = fmaf(tw1[1][1], s11, a1[c][1]);
            a2[c][0] = fmaf(tw2[0][0], s00, a2[c][0]);
            a2[c][0] = fmaf(tw2[1][0], s01, a2[c][0]);
            a2[c][1] = fmaf(tw2[0][1], s10, a2[c][1]);
            a2[c][1] = fmaf(tw2[1][1], s11, a2[c][1]);
            Lhi[c] = Llo; Rlo[c] = Rhi;
        }
    }

    {
        float t1e[2], t2e[2];
        #pragma unroll
        for (int p = 0; p < 2; ++p) {
            wv1[p] *= m1[p];
            float ta = (wv1[p] >= EPSW) ? wv1[p] : 0.f;
            t1e[p] = ta; S1[p] += ta;
            wv2[p] *= m2[p];
            float tb = (wv2[p] >= EPSW) ? wv2[p] : 0.f;
            t2e[p] = tb; S2[p] += tb;
        }
        const int li = bi0 - 32;
        const int ri = bi0 + 32;
        #pragma unroll
        for (int c = 0; c < 4; ++c) {
            float2 Lle = *(const float2*)&xs[(c0+c)*132 + li];
            float2 Rre = *(const float2*)&xs[(c0+c)*132 + ri];
            float s0 = Lle.y    + Rlo[c].y;
            float s1 = Lhi[c].x + Rre.x;
            a1[c][0] = fmaf(t1e[0], s0, a1[c][0]);
            a1[c][1] = fmaf(t1e[1], s1, a1[c][1]);
            a2[c][0] = fmaf(t2e[0], s0, a2[c][0]);
            a2[c][1] = fmaf(t2e[1], s1, a2[c][1]);
        }
    }

    float n1[2], n2[2];
    #pragma unroll
    for (int p = 0; p < 2; ++p) {
        n1[p] = 1.0f / (1.0f + 2.0f*S1[p] + 1e-8f);
        n2[p] = 1.0f / (1.0f + 2.0f*S2[p] + 1e-8f);
    }
    #pragma unroll
    for (int p = 0; p < 2; ++p) {
        uint4 pk;
        u32* pq = (u32*)&pk;
        #pragma unroll
        for (int c = 0; c < 4; ++c)
            pq[c] = (u32)f2bf(a1[c][p]*n1[p]) | ((u32)f2bf(a2[c][p]*n2[p]) << 16);
        *(uint4*)(ws + ((size_t)(b*HH + h)*WW + (w0g + p))*CC + c0) = pk;
    }
}

// ---------------- vertical pass (identical logic to R7; 128-VGPR budget) ----
// grid (32 = wg*2+chalf, 16 hblk, 4 b), block 1024 = 16 waves. Tile: 32w x
// 32h x 16c (c-half), both gaussians. K window 96 rows streamed in 3 chunks
// of 32 through LDS As[(w*16+c)*33 + r] (interleaved u32), prefetch in regs.
// 1024-thr block hardware-caps VGPR at 128; live ~110 fits -> no spill.
__global__ __launch_bounds__(1024)
void vpass(const u32* __restrict__ ws, const float* __restrict__ sig,
           float* __restrict__ out)
{
    extern __shared__ u32 As[];          // 16896 u32 = 67.6KB, aliased as f32 Dl
    const int t    = threadIdx.x;
    const int lane = t & 63;
    const int wid  = t >> 6;             // 0..15
    const int l15  = lane & 15;
    const int grp  = lane >> 4;

    const int bx    = blockIdx.x;
    const int chalf = bx & 1;
    const int w0    = (bx >> 1) * 32;
    const int h0    = blockIdx.y * 32;
    const int b     = blockIdx.z;
    const int c0    = chalf * 16;

    float ttl[2][2];
    #pragma unroll
    for (int wsel = 0; wsel < 2; ++wsel)
        #pragma unroll
        for (int ht = 0; ht < 2; ++ht) {
            float s = sig[((size_t)(b*HH + h0 + ht*16 + l15))*WW + w0 + 2*wid + wsel];
            ttl[wsel][ht] = -0.5f / (s*s);
        }

    const int srow = t >> 7;             // 0..7
    const int rem  = t & 127;
    const int sw   = rem >> 2;           // 0..31 (w)
    const int sc4  = rem & 3;            // 0..3  (c quad)
    const u32* wsb = ws + (size_t)b * HH * WW * CC;

    uint4 v[4];
    #pragma unroll
    for (int i = 0; i < 4; ++i) {
        int hh = reflect512(h0 - 32 + srow + 8*i);
        v[i] = *(const uint4*)&wsb[(size_t)(hh*WW + w0 + sw)*CC + c0 + sc4*4];
    }

    f32x4 acc[2][2][2];                  // [wsel][g][ht]
    float Sr[2][2][2];
    #pragma unroll
    for (int a = 0; a < 2; ++a)
        #pragma unroll
        for (int g = 0; g < 2; ++g)
            #pragma unroll
            for (int ht = 0; ht < 2; ++ht) {
                acc[a][g][ht] = (f32x4){0.f,0.f,0.f,0.f};
                Sr[a][g][ht] = 0.f;
            }

    #pragma unroll
    for (int kt = 0; kt < 3; ++kt) {
        if (kt) __syncthreads();
        #pragma unroll
        for (int i = 0; i < 4; ++i) {
            int rs = srow + 8*(i ^ (sw & 3));
            #pragma unroll
            for (int cc = 0; cc < 4; ++cc)
                As[(sw*16 + sc4*4 + cc)*33 + rs] = ((const u32*)&v[i])[cc];
        }
        if (kt < 2) {
            #pragma unroll
            for (int i = 0; i < 4; ++i) {
                int hh = reflect512(h0 - 32 + (kt+1)*32 + srow + 8*i);
                v[i] = *(const uint4*)&wsb[(size_t)(hh*WW + w0 + sw)*CC + c0 + sc4*4];
            }
        }
        __syncthreads();

        #pragma unroll
        for (int wsel = 0; wsel < 2; ++wsel) {
            const int wl = 2*wid + wsel;
            u32 raw[8];
            {
                const int base = (wl*16 + l15)*33 + (grp ^ (wl & 3))*8;
                #pragma unroll
                for (int j = 0; j < 8; ++j) raw[j] = As[base + j];
            }
            #pragma unroll
            for (int g = 0; g < 2; ++g) {
                BU af;
                #pragma unroll
                for (int i = 0; i < 4; ++i)
                    af.u[i] = g ? ((raw[2*i] >> 16) | (raw[2*i+1] & 0xffff0000u))
                                : ((raw[2*i] & 0xffffu) | (raw[2*i+1] << 16));
                #pragma unroll
                for (int ht = 0; ht < 2; ++ht) {
                    const float tt = ttl[wsel][ht] * (g ? 0.390625f : 1.0f);
                    const int d0 = kt*32 + grp*8 - (ht*16 + l15) - 32;
                    BU bfr;
                    float Sl = 0.f;
                    #pragma unroll
                    for (int j = 0; j < 8; ++j) {
                        int d = d0 + j;
                        float wf = __expf(tt * (float)(d*d));
                        bool ok = ((u32)(d + 31) <= 62u) && (wf >= EPSW);
                        float val = ok ? wf : 0.f;
                        Sl += val;
                        bfr.h[j] = f2bf(val);
                    }
                    Sr[wsel][g][ht] += Sl;
                    acc[wsel][g][ht] = __builtin_amdgcn_mfma_f32_16x16x32_bf16(
                        af.b, bfr.b, acc[wsel][g][ht], 0, 0, 0);
                }
            }
        }
    }

    // normalize + diff
    float dif[2][2][4];
    #pragma unroll
    for (int wsel = 0; wsel < 2; ++wsel)
        #pragma unroll
        for (int ht = 0; ht < 2; ++ht) {
            float n[2];
            #pragma unroll
            for (int g = 0; g < 2; ++g) {
                float S = Sr[wsel][g][ht];
                S += __shfl_xor(S, 16);
                S += __shfl_xor(S, 32);
                n[g] = 1.0f / (S + 1e-8f);
            }
            #pragma unroll
            for (int r = 0; r < 4; ++r)
                dif[wsel][ht][r] = acc[wsel][1][ht][r]*n[1] - acc[wsel][0][ht][r]*n[0];
        }

    // epilogue: transpose through LDS, full-128B-line stores
    __syncthreads();
    float* Dl = (float*)As;              // [c'16 x h32] rows, w pitch 33
    #pragma unroll
    for (int wsel = 0; wsel < 2; ++wsel)
        #pragma unroll
        for (int ht = 0; ht < 2; ++ht)
            #pragma unroll
            for (int r = 0; r < 4; ++r)
                Dl[((grp*4 + r)*32 + ht*16 + l15)*33 + 2*wid + wsel] = dif[wsel][ht][r];
    __syncthreads();
    {
        const int row  = t >> 1;         // 0..511 = c'(16) x h(32)
        const int cl   = row >> 5;
        const int hl   = row & 31;
        const int woff = (t & 1)*16;
        const float* src = &Dl[(cl*32 + hl)*33 + woff];
        float* dst = out + ((size_t)((b*CC + c0 + cl)*HH + h0 + hl))*WW + w0 + woff;
        #pragma unroll
        for (int k = 0; k < 4; ++k)
            *(float4*)(dst + 4*k) = *(const float4*)(src + 4*k);
    }
}

extern "C" void kernel_launch(void* const* d_in, const int* in_sizes, int n_in,
                              void* d_out, int out_size, void* d_ws, size_t ws_size,
                              hipStream_t stream) {
    const float* x   = (const float*)d_in[0];
    const float* sig = (const float*)d_in[1];
    float* out = (float*)d_out;

    const size_t n = (size_t)BB*CC*HH*WW;
    if (ws_size < n * sizeof(u32)) return;
    u32* ws = (u32*)d_ws;

    hpass<<<dim3(8, 512, 4), 256, 0, stream>>>(x, sig, ws);
    vpass<<<dim3(32, 16, 4), 1024, 16896*sizeof(u32), stream>>>(ws, sig, out);
}

// Round 9
// 885.681 us; speedup vs baseline: 2.1057x; 1.0681x over previous
//
#include <hip/hip_runtime.h>
#include <stdint.h>

typedef unsigned short u16;
typedef unsigned int   u32;

#define WW 512
#define HH 512
#define BB 4
#define CC 32
#define EPSW 1e-3f

typedef __bf16 bf16x8 __attribute__((ext_vector_type(8)));
typedef short  s16x8  __attribute__((ext_vector_type(8)));
typedef float  f32x4  __attribute__((ext_vector_type(4)));

union BU { u16 h[8]; u32 u[4]; bf16x8 b; s16x8 s; };

__device__ __forceinline__ int reflect512(int i) {
    i = (i < 0) ? -i : i;
    return (i >= WW) ? (2*WW - 2 - i) : i;
}
__device__ __forceinline__ u16 f2bf(float f) {
    u32 u = __float_as_uint(f);
    return (u16)((u + 0x7fffu + ((u >> 16) & 1u)) >> 16);
}

// ---------------- horizontal pass (logic proven R5-R8) ----------------------
// waves_per_eu(4,4): register budget 512/4 = 128 VGPR -> no spills.
__global__ __launch_bounds__(256) __attribute__((amdgpu_waves_per_eu(4, 4)))
void hpass(const float* __restrict__ x, const float* __restrict__ sig,
           u32* __restrict__ ws)
{
    __shared__ float xs[32*132];
    const int t  = threadIdx.x;
    const int wt = blockIdx.x;
    const int h  = blockIdx.y;
    const int b  = blockIdx.z;
    const int wbase = wt*64 - 32;

    {
        const int wi = t & 127;
        const int gw = reflect512(wbase + wi);
        #pragma unroll
        for (int rep = 0; rep < 16; ++rep) {
            int c = rep*2 + (t >> 7);
            xs[c*132 + wi] = x[((size_t)((b*CC + c)*HH + h))*WW + gw];
        }
    }
    __syncthreads();

    const int c0  = (t & 7)*4;
    const int wp  = t >> 3;
    const int w0g = wt*64 + wp*2;
    const int bi0 = 32 + wp*2;

    float2 sg = *(const float2*)(sig + ((size_t)(b*HH + h))*WW + w0g);

    float m1[2], q1[2], wv1[2], S1[2], m2[2], q2[2], wv2[2], S2[2];
    #pragma unroll
    for (int p = 0; p < 2; ++p) {
        float s   = p ? sg.y : sg.x;
        float tt1 = -0.5f / (s*s);
        m1[p] = __expf(tt1);             q1[p] = m1[p]*m1[p];
        float tt2 = tt1 * 0.390625f;
        m2[p] = __expf(tt2);             q2[p] = m2[p]*m2[p];
        wv1[p] = 1.f; wv2[p] = 1.f; S1[p] = 0.f; S2[p] = 0.f;
    }

    float a1[4][2], a2[4][2];
    float2 Lhi[4], Rlo[4];
    #pragma unroll
    for (int c = 0; c < 4; ++c) {
        float2 Cq = *(const float2*)&xs[(c0+c)*132 + bi0];
        a1[c][0] = Cq.x; a1[c][1] = Cq.y;
        a2[c][0] = Cq.x; a2[c][1] = Cq.y;
        Lhi[c] = Cq; Rlo[c] = Cq;
    }

    #pragma unroll 1
    for (int kb = 0; kb < 15; ++kb) {
        float tw1[2][2], tw2[2][2];
        #pragma unroll
        for (int j = 0; j < 2; ++j)
            #pragma unroll
            for (int p = 0; p < 2; ++p) {
                wv1[p] *= m1[p]; m1[p] *= q1[p];
                float ta = (wv1[p] >= EPSW) ? wv1[p] : 0.f;
                tw1[j][p] = ta; S1[p] += ta;
                wv2[p] *= m2[p]; m2[p] *= q2[p];
                float tb = (wv2[p] >= EPSW) ? wv2[p] : 0.f;
                tw2[j][p] = tb; S2[p] += tb;
            }
        const int li = bi0 - 2 - 2*kb;
        const int ri = bi0 + 2 + 2*kb;
        #pragma unroll
        for (int c = 0; c < 4; ++c) {
            float2 Llo = *(const float2*)&xs[(c0+c)*132 + li];
            float2 Rhi = *(const float2*)&xs[(c0+c)*132 + ri];
            float s00 = Llo.y    + Rlo[c].y;
            float s01 = Llo.x    + Rhi.x;
            float s10 = Lhi[c].x + Rhi.x;
            float s11 = Llo.y    + Rhi.y;
            a1[c][0] = fmaf(tw1[0][0], s00, a1[c][0]);
            a1[c][0] = fmaf(tw1[1][0], s01, a1[c][0]);
            a1[c][1] = fmaf(tw1[0][1], s10, a1[c][1]);
            a1[c][1] = fmaf(tw1[1][1], s11, a1[c][1]);
            a2[c][0] = fmaf(tw2[0][0], s00, a2[c][0]);
            a2[c][0] = fmaf(tw2[1][0], s01, a2[c][0]);
            a2[c][1] = fmaf(tw2[0][1], s10, a2[c][1]);
            a2[c][1] = fmaf(tw2[1][1], s11, a2[c][1]);
            Lhi[c] = Llo; Rlo[c] = Rhi;
        }
    }

    {
        float t1e[2], t2e[2];
        #pragma unroll
        for (int p = 0; p < 2; ++p) {
            wv1[p] *= m1[p];
            float ta = (wv1[p] >= EPSW) ? wv1[p] : 0.f;
            t1e[p] = ta; S1[p] += ta;
            wv2[p] *= m2[p];
            float tb = (wv2[p] >= EPSW) ? wv2[p] : 0.f;
            t2e[p] = tb; S2[p] += tb;
        }
        const int li = bi0 - 32;
        const int ri = bi0 + 32;
        #pragma unroll
        for (int c = 0; c < 4; ++c) {
            float2 Lle = *(const float2*)&xs[(c0+c)*132 + li];
            float2 Rre = *(const float2*)&xs[(c0+c)*132 + ri];
            float s0 = Lle.y    + Rlo[c].y;
            float s1 = Lhi[c].x + Rre.x;
            a1[c][0] = fmaf(t1e[0], s0, a1[c][0]);
            a1[c][1] = fmaf(t1e[1], s1, a1[c][1]);
            a2[c][0] = fmaf(t2e[0], s0, a2[c][0]);
            a2[c][1] = fmaf(t2e[1], s1, a2[c][1]);
        }
    }

    float n1[2], n2[2];
    #pragma unroll
    for (int p = 0; p < 2; ++p) {
        n1[p] = 1.0f / (1.0f + 2.0f*S1[p] + 1e-8f);
        n2[p] = 1.0f / (1.0f + 2.0f*S2[p] + 1e-8f);
    }
    #pragma unroll
    for (int p = 0; p < 2; ++p) {
        uint4 pk;
        u32* pq = (u32*)&pk;
        #pragma unroll
        for (int c = 0; c < 4; ++c)
            pq[c] = (u32)f2bf(a1[c][p]*n1[p]) | ((u32)f2bf(a2[c][p]*n2[p]) << 16);
        *(uint4*)(ws + ((size_t)(b*HH + h)*WW + (w0g + p))*CC + c0) = pk;
    }
}

// ---------------- vertical pass (logic proven R7/R8) ------------------------
// waves_per_eu(4,4): register budget 512/4 = 128 VGPR (live ~110) -> no
// spills; 16-wave block = 1 block/CU (dynamic LDS 67.6KB allows 2, VGPR 1).
__global__ __launch_bounds__(1024) __attribute__((amdgpu_waves_per_eu(4, 4)))
void vpass(const u32* __restrict__ ws, const float* __restrict__ sig,
           float* __restrict__ out)
{
    extern __shared__ u32 As[];          // 16896 u32 = 67.6KB, aliased as f32 Dl
    const int t    = threadIdx.x;
    const int lane = t & 63;
    const int wid  = t >> 6;             // 0..15
    const int l15  = lane & 15;
    const int grp  = lane >> 4;

    const int bx    = blockIdx.x;
    const int chalf = bx & 1;
    const int w0    = (bx >> 1) * 32;
    const int h0    = blockIdx.y * 32;
    const int b     = blockIdx.z;
    const int c0    = chalf * 16;

    float ttl[2][2];
    #pragma unroll
    for (int wsel = 0; wsel < 2; ++wsel)
        #pragma unroll
        for (int ht = 0; ht < 2; ++ht) {
            float s = sig[((size_t)(b*HH + h0 + ht*16 + l15))*WW + w0 + 2*wid + wsel];
            ttl[wsel][ht] = -0.5f / (s*s);
        }

    const int srow = t >> 7;             // 0..7
    const int rem  = t & 127;
    const int sw   = rem >> 2;           // 0..31 (w)
    const int sc4  = rem & 3;            // 0..3  (c quad)
    const u32* wsb = ws + (size_t)b * HH * WW * CC;

    uint4 v[4];
    #pragma unroll
    for (int i = 0; i < 4; ++i) {
        int hh = reflect512(h0 - 32 + srow + 8*i);
        v[i] = *(const uint4*)&wsb[(size_t)(hh*WW + w0 + sw)*CC + c0 + sc4*4];
    }

    f32x4 acc[2][2][2];                  // [wsel][g][ht]
    float Sr[2][2][2];
    #pragma unroll
    for (int a = 0; a < 2; ++a)
        #pragma unroll
        for (int g = 0; g < 2; ++g)
            #pragma unroll
            for (int ht = 0; ht < 2; ++ht) {
                acc[a][g][ht] = (f32x4){0.f,0.f,0.f,0.f};
                Sr[a][g][ht] = 0.f;
            }

    #pragma unroll
    for (int kt = 0; kt < 3; ++kt) {
        if (kt) __syncthreads();
        #pragma unroll
        for (int i = 0; i < 4; ++i) {
            int rs = srow + 8*(i ^ (sw & 3));
            #pragma unroll
            for (int cc = 0; cc < 4; ++cc)
                As[(sw*16 + sc4*4 + cc)*33 + rs] = ((const u32*)&v[i])[cc];
        }
        if (kt < 2) {
            #pragma unroll
            for (int i = 0; i < 4; ++i) {
                int hh = reflect512(h0 - 32 + (kt+1)*32 + srow + 8*i);
                v[i] = *(const uint4*)&wsb[(size_t)(hh*WW + w0 + sw)*CC + c0 + sc4*4];
            }
        }
        __syncthreads();

        #pragma unroll
        for (int wsel = 0; wsel < 2; ++wsel) {
            const int wl = 2*wid + wsel;
            u32 raw[8];
            {
                const int base = (wl*16 + l15)*33 + (grp ^ (wl & 3))*8;
                #pragma unroll
                for (int j = 0; j < 8; ++j) raw[j] = As[base + j];
            }
            #pragma unroll
            for (int g = 0; g < 2; ++g) {
                BU af;
                #pragma unroll
                for (int i = 0; i < 4; ++i)
                    af.u[i] = g ? ((raw[2*i] >> 16) | (raw[2*i+1] & 0xffff0000u))
                                : ((raw[2*i] & 0xffffu) | (raw[2*i+1] << 16));
                #pragma unroll
                for (int ht = 0; ht < 2; ++ht) {
                    const float tt = ttl[wsel][ht] * (g ? 0.390625f : 1.0f);
                    const int d0 = kt*32 + grp*8 - (ht*16 + l15) - 32;
                    BU bfr;
                    float Sl = 0.f;
                    #pragma unroll
                    for (int j = 0; j < 8; ++j) {
                        int d = d0 + j;
                        float wf = __expf(tt * (float)(d*d));
                        bool ok = ((u32)(d + 31) <= 62u) && (wf >= EPSW);
                        float val = ok ? wf : 0.f;
                        Sl += val;
                        bfr.h[j] = f2bf(val);
                    }
                    Sr[wsel][g][ht] += Sl;
                    acc[wsel][g][ht] = __builtin_amdgcn_mfma_f32_16x16x32_bf16(
                        af.b, bfr.b, acc[wsel][g][ht], 0, 0, 0);
                }
            }
        }
    }

    // normalize + diff
    float dif[2][2][4];
    #pragma unroll
    for (int wsel = 0; wsel < 2; ++wsel)
        #pragma unroll
        for (int ht = 0; ht < 2; ++ht) {
            float n[2];
            #pragma unroll
            for (int g = 0; g < 2; ++g) {
                float S = Sr[wsel][g][ht];
                S += __shfl_xor(S, 16);
                S += __shfl_xor(S, 32);
                n[g] = 1.0f / (S + 1e-8f);
            }
            #pragma unroll
            for (int r = 0; r < 4; ++r)
                dif[wsel][ht][r] = acc[wsel][1][ht][r]*n[1] - acc[wsel][0][ht][r]*n[0];
        }

    // epilogue: transpose through LDS, full-128B-line stores
    __syncthreads();
    float* Dl = (float*)As;              // [c'16 x h32] rows, w pitch 33
    #pragma unroll
    for (int wsel = 0; wsel < 2; ++wsel)
        #pragma unroll
        for (int ht = 0; ht < 2; ++ht)
            #pragma unroll
            for (int r = 0; r < 4; ++r)
                Dl[((grp*4 + r)*32 + ht*16 + l15)*33 + 2*wid + wsel] = dif[wsel][ht][r];
    __syncthreads();
    {
        const int row  = t >> 1;         // 0..511 = c'(16) x h(32)
        const int cl   = row >> 5;
        const int hl   = row & 31;
        const int woff = (t & 1)*16;
        const float* src = &Dl[(cl*32 + hl)*33 + woff];
        float* dst = out + ((size_t)((b*CC + c0 + cl)*HH + h0 + hl))*WW + w0 + woff;
        #pragma unroll
        for (int k = 0; k < 4; ++k)
            *(float4*)(dst + 4*k) = *(const float4*)(src + 4*k);
    }
}

extern "C" void kernel_launch(void* const* d_in, const int* in_sizes, int n_in,
                              void* d_out, int out_size, void* d_ws, size_t ws_size,
                              hipStream_t stream) {
    const float* x   = (const float*)d_in[0];
    const float* sig = (const float*)d_in[1];
    float* out = (float*)d_out;

    const size_t n = (size_t)BB*CC*HH*WW;
    if (ws_size < n * sizeof(u32)) return;
    u32* ws = (u32*)d_ws;

    hpass<<<dim3(8, 512, 4), 256, 0, stream>>>(x, sig, ws);
    vpass<<<dim3(32, 16, 4), 1024, 16896*sizeof(u32), stream>>>(ws, sig, out);
}

// Round 10
// 811.812 us; speedup vs baseline: 2.2973x; 1.0910x over previous
//
#include <hip/hip_runtime.h>
#include <stdint.h>

typedef unsigned short u16;
typedef unsigned int   u32;

#define WW 512
#define HH 512
#define BB 4
#define CC 32
#define EPSW 1e-3f

typedef __bf16 bf16x8 __attribute__((ext_vector_type(8)));
typedef short  s16x8  __attribute__((ext_vector_type(8)));
typedef float  f32x4  __attribute__((ext_vector_type(4)));

union BU { u16 h[8]; u32 u[4]; bf16x8 b; s16x8 s; };

__device__ __forceinline__ int reflect512(int i) {
    i = (i < 0) ? -i : i;
    return (i >= WW) ? (2*WW - 2 - i) : i;
}
__device__ __forceinline__ u16 f2bf(float f) {
    u32 u = __float_as_uint(f);
    return (u16)((u + 0x7fffu + ((u >> 16) & 1u)) >> 16);
}

// ---------------- horizontal pass: 512 thr, 2c x 2w per thread --------------
// Live regs ~56 -> fits the 64-VGPR budget (8 waves/SIMD heuristic), no spill.
__global__ __launch_bounds__(512)
void hpass(const float* __restrict__ x, const float* __restrict__ sig,
           u32* __restrict__ ws)
{
    __shared__ float xs[32*132];
    const int t  = threadIdx.x;
    const int wt = blockIdx.x;
    const int h  = blockIdx.y;
    const int b  = blockIdx.z;
    const int wbase = wt*64 - 32;

    {   // stage 32c x 128w reflected window
        const int wi = t & 127;
        const int gw = reflect512(wbase + wi);
        const int cb = t >> 7;                 // 0..3
        #pragma unroll
        for (int rep = 0; rep < 8; ++rep) {
            int c = rep*4 + cb;
            xs[c*132 + wi] = x[((size_t)((b*CC + c)*HH + h))*WW + gw];
        }
    }
    __syncthreads();

    const int c0  = (t & 15)*2;                // 0,2,..,30
    const int wp  = t >> 4;                    // 0..31
    const int w0g = wt*64 + wp*2;
    const int bi0 = 32 + wp*2;

    float2 sg = *(const float2*)(sig + ((size_t)(b*HH + h))*WW + w0g);

    float m1[2], q1[2], wv1[2], S1[2], m2[2], q2[2], wv2[2], S2[2];
    #pragma unroll
    for (int p = 0; p < 2; ++p) {
        float s   = p ? sg.y : sg.x;
        float tt1 = -0.5f / (s*s);
        m1[p] = __expf(tt1);             q1[p] = m1[p]*m1[p];
        float tt2 = tt1 * 0.390625f;     // sigma2 = 1.6*sigma
        m2[p] = __expf(tt2);             q2[p] = m2[p]*m2[p];
        wv1[p] = 1.f; wv2[p] = 1.f; S1[p] = 0.f; S2[p] = 0.f;
    }

    float a1[2][2], a2[2][2];
    float2 Lhi[2], Rlo[2];
    #pragma unroll
    for (int c = 0; c < 2; ++c) {
        float2 Cq = *(const float2*)&xs[(c0+c)*132 + bi0];
        a1[c][0] = Cq.x; a1[c][1] = Cq.y;
        a2[c][0] = Cq.x; a2[c][1] = Cq.y;
        Lhi[c] = Cq; Rlo[c] = Cq;
    }

    #pragma unroll 1
    for (int kb = 0; kb < 15; ++kb) {          // taps k = 2kb+1, 2kb+2
        float tw1[2][2], tw2[2][2];
        #pragma unroll
        for (int j = 0; j < 2; ++j)
            #pragma unroll
            for (int p = 0; p < 2; ++p) {
                wv1[p] *= m1[p]; m1[p] *= q1[p];
                float ta = (wv1[p] >= EPSW) ? wv1[p] : 0.f;
                tw1[j][p] = ta; S1[p] += ta;
                wv2[p] *= m2[p]; m2[p] *= q2[p];
                float tb = (wv2[p] >= EPSW) ? wv2[p] : 0.f;
                tw2[j][p] = tb; S2[p] += tb;
            }
        const int li = bi0 - 2 - 2*kb;
        const int ri = bi0 + 2 + 2*kb;
        #pragma unroll
        for (int c = 0; c < 2; ++c) {
            float2 Llo = *(const float2*)&xs[(c0+c)*132 + li];
            float2 Rhi = *(const float2*)&xs[(c0+c)*132 + ri];
            float s00 = Llo.y    + Rlo[c].y;
            float s01 = Llo.x    + Rhi.x;
            float s10 = Lhi[c].x + Rhi.x;
            float s11 = Llo.y    + Rhi.y;
            a1[c][0] = fmaf(tw1[0][0], s00, a1[c][0]);
            a1[c][0] = fmaf(tw1[1][0], s01, a1[c][0]);
            a1[c][1] = fmaf(tw1[0][1], s10, a1[c][1]);
            a1[c][1] = fmaf(tw1[1][1], s11, a1[c][1]);
            a2[c][0] = fmaf(tw2[0][0], s00, a2[c][0]);
            a2[c][0] = fmaf(tw2[1][0], s01, a2[c][0]);
            a2[c][1] = fmaf(tw2[0][1], s10, a2[c][1]);
            a2[c][1] = fmaf(tw2[1][1], s11, a2[c][1]);
            Lhi[c] = Llo; Rlo[c] = Rhi;
        }
    }

    {   // epilogue tap k = 31
        float t1e[2], t2e[2];
        #pragma unroll
        for (int p = 0; p < 2; ++p) {
            wv1[p] *= m1[p];
            float ta = (wv1[p] >= EPSW) ? wv1[p] : 0.f;
            t1e[p] = ta; S1[p] += ta;
            wv2[p] *= m2[p];
            float tb = (wv2[p] >= EPSW) ? wv2[p] : 0.f;
            t2e[p] = tb; S2[p] += tb;
        }
        const int li = bi0 - 32;
        const int ri = bi0 + 32;
        #pragma unroll
        for (int c = 0; c < 2; ++c) {
            float2 Lle = *(const float2*)&xs[(c0+c)*132 + li];
            float2 Rre = *(const float2*)&xs[(c0+c)*132 + ri];
            float s0 = Lle.y    + Rlo[c].y;
            float s1 = Lhi[c].x + Rre.x;
            a1[c][0] = fmaf(t1e[0], s0, a1[c][0]);
            a1[c][1] = fmaf(t1e[1], s1, a1[c][1]);
            a2[c][0] = fmaf(t2e[0], s0, a2[c][0]);
            a2[c][1] = fmaf(t2e[1], s1, a2[c][1]);
        }
    }

    float n1[2], n2[2];
    #pragma unroll
    for (int p = 0; p < 2; ++p) {
        n1[p] = 1.0f / (1.0f + 2.0f*S1[p] + 1e-8f);
        n2[p] = 1.0f / (1.0f + 2.0f*S2[p] + 1e-8f);
    }
    #pragma unroll
    for (int p = 0; p < 2; ++p) {
        uint2 pk;
        pk.x = (u32)f2bf(a1[0][p]*n1[p]) | ((u32)f2bf(a2[0][p]*n2[p]) << 16);
        pk.y = (u32)f2bf(a1[1][p]*n1[p]) | ((u32)f2bf(a2[1][p]*n2[p]) << 16);
        *(uint2*)(ws + ((size_t)(b*HH + h)*WW + (w0g + p))*CC + c0) = pk;
    }
}

// ---------------- vertical pass (MFMA, static double-buffered LDS) ----------
// grid (32 = wg*2+chalf, 16 hblk, 4 b), block 1024 = 16 waves. Tile: 32w x
// 32h x 16c (c-half), both gaussians. K window 96 rows in 3 chunks of 32.
// STATIC LDS 135KB (2 buffers) -> allocator sees 1 block/CU = 4 waves/SIMD
// -> 128-VGPR budget (R3-verified heuristic); live ~110 -> no spills.
// Pipeline: issue loads(kt+1) -> compute buf[kt&1] -> write buf[(kt+1)&1] -> bar.
__global__ __launch_bounds__(1024)
void vpass(const u32* __restrict__ ws, const float* __restrict__ sig,
           float* __restrict__ out)
{
    __shared__ u32 As[2][16896];         // 135.2 KB static, buf[0] aliased as Dl
    const int t    = threadIdx.x;
    const int lane = t & 63;
    const int wid  = t >> 6;             // 0..15
    const int l15  = lane & 15;
    const int grp  = lane >> 4;

    const int bx    = blockIdx.x;
    const int chalf = bx & 1;
    const int w0    = (bx >> 1) * 32;
    const int h0    = blockIdx.y * 32;
    const int b     = blockIdx.z;
    const int c0    = chalf * 16;

    float ttl[2][2];
    #pragma unroll
    for (int wsel = 0; wsel < 2; ++wsel)
        #pragma unroll
        for (int ht = 0; ht < 2; ++ht) {
            float s = sig[((size_t)(b*HH + h0 + ht*16 + l15))*WW + w0 + 2*wid + wsel];
            ttl[wsel][ht] = -0.5f / (s*s);
        }

    const int srow = t >> 7;             // 0..7
    const int rem  = t & 127;
    const int sw   = rem >> 2;           // 0..31 (w)
    const int sc4  = rem & 3;            // 0..3  (c quad)
    const u32* wsb = ws + (size_t)b * HH * WW * CC;

    // prologue: stage chunk 0 into buf 0
    {
        uint4 v0[4];
        #pragma unroll
        for (int i = 0; i < 4; ++i) {
            int hh = reflect512(h0 - 32 + srow + 8*i);
            v0[i] = *(const uint4*)&wsb[(size_t)(hh*WW + w0 + sw)*CC + c0 + sc4*4];
        }
        #pragma unroll
        for (int i = 0; i < 4; ++i) {
            int rs = srow + 8*(i ^ (sw & 3));
            #pragma unroll
            for (int cc = 0; cc < 4; ++cc)
                As[0][(sw*16 + sc4*4 + cc)*33 + rs] = ((const u32*)&v0[i])[cc];
        }
    }
    __syncthreads();

    f32x4 acc[2][2][2];                  // [wsel][g][ht]
    float Sr[2][2][2];
    #pragma unroll
    for (int a = 0; a < 2; ++a)
        #pragma unroll
        for (int g = 0; g < 2; ++g)
            #pragma unroll
            for (int ht = 0; ht < 2; ++ht) {
                acc[a][g][ht] = (f32x4){0.f,0.f,0.f,0.f};
                Sr[a][g][ht] = 0.f;
            }

    #pragma unroll
    for (int kt = 0; kt < 3; ++kt) {
        const int cur = kt & 1;
        uint4 v[4];
        if (kt < 2) {                    // issue next chunk's loads (latency
            #pragma unroll               //  hidden under compute below)
            for (int i = 0; i < 4; ++i) {
                int hh = reflect512(h0 - 32 + (kt+1)*32 + srow + 8*i);
                v[i] = *(const uint4*)&wsb[(size_t)(hh*WW + w0 + sw)*CC + c0 + sc4*4];
            }
        }

        #pragma unroll
        for (int wsel = 0; wsel < 2; ++wsel) {
            const int wl = 2*wid + wsel;
            u32 raw[8];
            {
                const int base = (wl*16 + l15)*33 + (grp ^ (wl & 3))*8;
                #pragma unroll
                for (int j = 0; j < 8; ++j) raw[j] = As[cur][base + j];
            }
            #pragma unroll
            for (int g = 0; g < 2; ++g) {
                BU af;
                #pragma unroll
                for (int i = 0; i < 4; ++i)
                    af.u[i] = g ? ((raw[2*i] >> 16) | (raw[2*i+1] & 0xffff0000u))
                                : ((raw[2*i] & 0xffffu) | (raw[2*i+1] << 16));
                #pragma unroll
                for (int ht = 0; ht < 2; ++ht) {
                    const float tt = ttl[wsel][ht] * (g ? 0.390625f : 1.0f);
                    const int d0 = kt*32 + grp*8 - (ht*16 + l15) - 32;
                    BU bfr;
                    float Sl = 0.f;
                    #pragma unroll
                    for (int j = 0; j < 8; ++j) {
                        int d = d0 + j;
                        float wf = __expf(tt * (float)(d*d));
                        bool ok = ((u32)(d + 31) <= 62u) && (wf >= EPSW);
                        float val = ok ? wf : 0.f;
                        Sl += val;
                        bfr.h[j] = f2bf(val);
                    }
                    Sr[wsel][g][ht] += Sl;
                    acc[wsel][g][ht] = __builtin_amdgcn_mfma_f32_16x16x32_bf16(
                        af.b, bfr.b, acc[wsel][g][ht], 0, 0, 0);
                }
            }
        }

        if (kt < 2) {                    // write prefetched chunk to other buf
            #pragma unroll
            for (int i = 0; i < 4; ++i) {
                int rs = srow + 8*(i ^ (sw & 3));
                #pragma unroll
                for (int cc = 0; cc < 4; ++cc)
                    As[cur ^ 1][(sw*16 + sc4*4 + cc)*33 + rs] = ((const u32*)&v[i])[cc];
            }
        }
        __syncthreads();
    }

    // normalize + diff
    float dif[2][2][4];
    #pragma unroll
    for (int wsel = 0; wsel < 2; ++wsel)
        #pragma unroll
        for (int ht = 0; ht < 2; ++ht) {
            float n[2];
            #pragma unroll
            for (int g = 0; g < 2; ++g) {
                float S = Sr[wsel][g][ht];
                S += __shfl_xor(S, 16);
                S += __shfl_xor(S, 32);
                n[g] = 1.0f / (S + 1e-8f);
            }
            #pragma unroll
            for (int r = 0; r < 4; ++r)
                dif[wsel][ht][r] = acc[wsel][1][ht][r]*n[1] - acc[wsel][0][ht][r]*n[0];
        }

    // epilogue: transpose through LDS (buf0), full-128B-line stores
    __syncthreads();
    float* Dl = (float*)&As[0][0];       // [c'16 x h32] rows, w pitch 33
    #pragma unroll
    for (int wsel = 0; wsel < 2; ++wsel)
        #pragma unroll
        for (int ht = 0; ht < 2; ++ht)
            #pragma unroll
            for (int r = 0; r < 4; ++r)
                Dl[((grp*4 + r)*32 + ht*16 + l15)*33 + 2*wid + wsel] = dif[wsel][ht][r];
    __syncthreads();
    {
        const int row  = t >> 1;         // 0..511 = c'(16) x h(32)
        const int cl   = row >> 5;
        const int hl   = row & 31;
        const int woff = (t & 1)*16;
        const float* src = &Dl[(cl*32 + hl)*33 + woff];
        float* dst = out + ((size_t)((b*CC + c0 + cl)*HH + h0 + hl))*WW + w0 + woff;
        #pragma unroll
        for (int k = 0; k < 4; ++k)
            *(float4*)(dst + 4*k) = *(const float4*)(src + 4*k);
    }
}

extern "C" void kernel_launch(void* const* d_in, const int* in_sizes, int n_in,
                              void* d_out, int out_size, void* d_ws, size_t ws_size,
                              hipStream_t stream) {
    const float* x   = (const float*)d_in[0];
    const float* sig = (const float*)d_in[1];
    float* out = (float*)d_out;

    const size_t n = (size_t)BB*CC*HH*WW;
    if (ws_size < n * sizeof(u32)) return;
    u32* ws = (u32*)d_ws;

    hpass<<<dim3(8, 512, 4), 512, 0, stream>>>(x, sig, ws);
    vpass<<<dim3(32, 16, 4), 1024, 0, stream>>>(ws, sig, out);
}